// Round 10
// baseline (66.907 us; speedup 1.0000x reference)
//
#include <hip/hip_runtime.h>
#include <hip/hip_bf16.h>

// ClassBalancedSupConLoss, B=8192, D=128.
// loss_i = -(BASE/t_i)*[P_i - C_i*lse_i]/(C_i+eps)
//   P_i   = invt_i*(e_i.S_{c(i)} - ||e_i||^2)      (fp32 closed form)
//   C_i   = count_{c(i)} - 1
//   lse_i = invt_i*||e_i||^2 + ln(Z_i),  Z_i = sum_j exp2(v_ij - m_i),
//           m_i = invt_i*log2e*||e_i||^2 (fixed reference; exact identity)
// k2 (r10): W=1 dual-chain 32x32x16 MFMA, swapped operands, B pre-scaled
// (Ebs). LATENCY-BOUND fix: minimal register footprint (~115 VGPR; no
// manual A dbuf, single B tile) + __launch_bounds__(256,4) -> 4 waves/SIMD,
// grid 1024 = 4 blocks/CU resident. TLP hides load/MFMA/exp latency
// (r9 showed 2 waves/SIMD leaves ~80% idle; manual prefetch didn't help).
// Ebf/Ebs in MFMA-fragment-tiled order (validated r4+):
//   (r,k) -> tile r>>5, chunk k>>4, lane (r&31)+((k>>3)&1)*32, e k&7.
// LESSON r8: launch_bounds min-waves arg caps VGPRs; here cap=128 >= need.
// Cross-block reductions: fixed-point int64 atomics (deterministic);
// final scalar via last-block ticket in k3.

#define B_ROWS 8192
#define D_DIM 128
#define NSPLIT 16
#define JRANGE (B_ROWS / NSPLIT)     // 512
#define NSTEPS (JRANGE / 32)         // 16
#define BASE_TEMP 0.07f
#define LOG2E 1.4426950408889634f
#define LN2 0.6931471805599453f
#define FIX_SCALE 1048576.0f         // 2^20

typedef __bf16 bf16x8 __attribute__((ext_vector_type(8)));
typedef __bf16 bf16x4 __attribute__((ext_vector_type(4)));
typedef float floatx16 __attribute__((ext_vector_type(16)));
typedef unsigned long long u64;

__device__ __forceinline__ float class_invtemp(int lbl) {
    return (lbl == 0) ? 12.5f : ((lbl == 1) ? 20.0f : 10.0f);
}

__device__ __forceinline__ u64 fix64(float v) {
    return (u64)(long long)llrintf(v * FIX_SCALE);
}

// ---- KZ: zero the 4 KB atomic-accumulator region ----
__global__ __launch_bounds__(256) void kz_zero(u64* __restrict__ a) {
    a[threadIdx.x] = 0ull;
    a[256 + threadIdx.x] = 0ull;
}

// ---- K0: cast->tiled Ebf + pre-scaled Ebs + row norms; class sums/counts ----
__global__ __launch_bounds__(256) void k0_prep(
        const float* __restrict__ E, const int* __restrict__ labels,
        __bf16* __restrict__ Ebf, __bf16* __restrict__ Ebs,
        float* __restrict__ nrm,
        u64* __restrict__ Sfix /*[3*128]*/, u64* __restrict__ cntfix /*[3]*/) {
    const int blk = blockIdx.x;          // 256 blocks x 32 rows
    const int tid = threadIdx.x;
    const int row0 = blk * 32;

    __shared__ float sh[3][128];
    __shared__ int scnt[3];
    if (tid < 3) scnt[tid] = 0;

    // pass 1: cast to tiled fragment layout (+scaled copy) + row norms
    const float4* src = reinterpret_cast<const float4*>(E + (size_t)row0 * D_DIM);
    #pragma unroll
    for (int p = 0; p < 4; ++p) {
        int idx = p * 256 + tid;         // 1024 float4 = 32 rows x 32 k4
        float4 v = src[idx];
        int r = idx >> 5, k4 = idx & 31;
        int R = row0 + r;
        float sc = class_invtemp(labels[R]) * LOG2E;
        int T = R >> 5;
        int l = (R & 31) + ((k4 >> 1) & 1) * 32;
        int c = k4 >> 2;
        size_t dst = (size_t)T * 4096 + c * 512 + l * 8 + (k4 & 1) * 4;
        bf16x4 o  = { (__bf16)v.x, (__bf16)v.y, (__bf16)v.z, (__bf16)v.w };
        bf16x4 os = { (__bf16)(v.x * sc), (__bf16)(v.y * sc),
                      (__bf16)(v.z * sc), (__bf16)(v.w * sc) };
        *reinterpret_cast<bf16x4*>(Ebf + dst) = o;
        *reinterpret_cast<bf16x4*>(Ebs + dst) = os;
        float s = v.x * v.x + v.y * v.y + v.z * v.z + v.w * v.w;
        s += __shfl_xor(s, 1);  s += __shfl_xor(s, 2);  s += __shfl_xor(s, 4);
        s += __shfl_xor(s, 8);  s += __shfl_xor(s, 16);
        if ((tid & 31) == 0) nrm[R] = s;   // 32 consecutive lanes = one row
    }

    // pass 2: class sums (L1/L2-hot), fixed-point atomics
    const int d = tid & 127, half = tid >> 7;
    float s0 = 0.f, s1 = 0.f, s2 = 0.f;
    #pragma unroll 4
    for (int r2 = 0; r2 < 16; ++r2) {
        int r = row0 + half * 16 + r2;
        float v = E[(size_t)r * D_DIM + d];
        int l = labels[r];
        s0 += (l == 0) ? v : 0.f;
        s1 += (l == 1) ? v : 0.f;
        s2 += (l == 2) ? v : 0.f;
    }
    if (half == 1) { sh[0][d] = s0; sh[1][d] = s1; sh[2][d] = s2; }
    if (tid < 32) atomicAdd(&scnt[labels[row0 + tid]], 1);
    __syncthreads();
    if (half == 0) {
        atomicAdd(&Sfix[d],       fix64(s0 + sh[0][d]));
        atomicAdd(&Sfix[128 + d], fix64(s1 + sh[1][d]));
        atomicAdd(&Sfix[256 + d], fix64(s2 + sh[2][d]));
    }
    __syncthreads();
    if (tid < 3) atomicAdd(&cntfix[tid], (u64)scnt[tid]);
}

// ---- K2: lean W=1 dual-chain MFMA, 4 waves/SIMD, fixed-m denominators ----
// grid (64 itiles, NSPLIT); block 256 = 4 waves; wave owns 32 i-cols.
__global__ __launch_bounds__(256, 4) void k2_stats(
        const __bf16* __restrict__ Ebf, const __bf16* __restrict__ Ebs,
        const int* __restrict__ labels, const float* __restrict__ nrm,
        float* __restrict__ part /*[NSPLIT][B]*/) {
    const int tid = threadIdx.x;
    const int lane = tid & 63;
    const int wave = tid >> 6;
    const int itile = blockIdx.x;        // 0..63 (128 i-cols per block)
    const int split = blockIdx.y;        // 0..NSPLIT-1
    const int col = lane & 31;
    const int icol = itile * 128 + wave * 32 + col;

    const float bscale = class_invtemp(labels[icol]) * LOG2E;
    const float negm = -bscale * nrm[icol];

    // B frag (i side), pre-scaled (Ebs), register-resident (32 VGPR)
    const int iT = itile * 4 + wave;
    const __bf16* bbase = Ebs + (size_t)iT * 4096 + lane * 8;
    bf16x8 Bf[8];
    #pragma unroll
    for (int c = 0; c < 8; ++c)
        Bf[c] = *reinterpret_cast<const bf16x8*>(bbase + c * 512);

    // A tiles (j side): Ebf tiles [split*NSTEPS, +NSTEPS)
    const __bf16* abase = Ebf + (size_t)split * NSTEPS * 4096 + lane * 8;

    float Zacc[4];
    #pragma unroll
    for (int q = 0; q < 4; ++q) Zacc[q] = 0.f;

    for (int s = 0; s < NSTEPS; ++s) {
        // single-buffer A loads; 4 waves/SIMD TLP hides the latency
        const __bf16* ap = abase + (size_t)s * 4096;
        bf16x8 A[8];
        #pragma unroll
        for (int c = 0; c < 8; ++c)
            A[c] = *reinterpret_cast<const bf16x8*>(ap + c * 512);

        // dual-chain MFMA (a0 chunks 0-3 init -m, a1 chunks 4-7 init 0)
        floatx16 a0, a1;
        #pragma unroll
        for (int r = 0; r < 16; ++r) { a0[r] = negm; a1[r] = 0.f; }
        a0 = __builtin_amdgcn_mfma_f32_32x32x16_bf16(A[0], Bf[0], a0, 0, 0, 0);
        a1 = __builtin_amdgcn_mfma_f32_32x32x16_bf16(A[4], Bf[4], a1, 0, 0, 0);
        a0 = __builtin_amdgcn_mfma_f32_32x32x16_bf16(A[1], Bf[1], a0, 0, 0, 0);
        a1 = __builtin_amdgcn_mfma_f32_32x32x16_bf16(A[5], Bf[5], a1, 0, 0, 0);
        a0 = __builtin_amdgcn_mfma_f32_32x32x16_bf16(A[2], Bf[2], a0, 0, 0, 0);
        a1 = __builtin_amdgcn_mfma_f32_32x32x16_bf16(A[6], Bf[6], a1, 0, 0, 0);
        a0 = __builtin_amdgcn_mfma_f32_32x32x16_bf16(A[3], Bf[3], a0, 0, 0, 0);
        a1 = __builtin_amdgcn_mfma_f32_32x32x16_bf16(A[7], Bf[7], a1, 0, 0, 0);

        #pragma unroll
        for (int q = 0; q < 4; ++q) {
            float z = (__builtin_amdgcn_exp2f(a0[4 * q]     + a1[4 * q])
                     + __builtin_amdgcn_exp2f(a0[4 * q + 1] + a1[4 * q + 1]))
                    + (__builtin_amdgcn_exp2f(a0[4 * q + 2] + a1[4 * q + 2])
                     + __builtin_amdgcn_exp2f(a0[4 * q + 3] + a1[4 * q + 3]));
            Zacc[q] += z;
        }
    }

    float Zt = (Zacc[0] + Zacc[1]) + (Zacc[2] + Zacc[3]);
    Zt += __shfl_xor(Zt, 32);            // lanes l, l+32 hold same i-col
    if (lane < 32)
        part[(size_t)split * B_ROWS + icol] = Zt;
}

// ---- K3: per-row loss (8 thr/row), fixed-point accumulate + ticket ----
__global__ __launch_bounds__(256) void k3_rowloss(
        const float* __restrict__ E, const int* __restrict__ labels,
        const u64* __restrict__ Sfix, const u64* __restrict__ cntfix,
        const float* __restrict__ nrm, const float* __restrict__ part,
        u64* __restrict__ lossfix, u64* __restrict__ validfix,
        unsigned int* __restrict__ done, float* __restrict__ out) {
    __shared__ float sS[384];
    const int tid = threadIdx.x;
    if (tid < 128) {
        sS[tid]       = (float)(long long)Sfix[tid]       * (1.0f / FIX_SCALE);
        sS[128 + tid] = (float)(long long)Sfix[128 + tid] * (1.0f / FIX_SCALE);
        sS[256 + tid] = (float)(long long)Sfix[256 + tid] * (1.0f / FIX_SCALE);
    }
    __syncthreads();

    const int r = tid >> 3, g = tid & 7;       // 32 rows/block, 8 thr/row
    const int i = blockIdx.x * 32 + r;
    const int lab = labels[i];
    const float invt = class_invtemp(lab);

    const float4* er = reinterpret_cast<const float4*>(E + (size_t)i * D_DIM);
    const float4* sr = reinterpret_cast<const float4*>(&sS[lab * 128]);
    float dotS = 0.f;
    #pragma unroll
    for (int q = 0; q < 4; ++q) {
        float4 v = er[g * 4 + q];
        float4 s = sr[g * 4 + q];
        dotS += v.x * s.x + v.y * s.y + v.z * s.z + v.w * s.w;
    }
    float Zp = 0.f;
    #pragma unroll
    for (int p = 0; p < NSPLIT / 8; ++p)
        Zp += part[(size_t)(g + p * 8) * B_ROWS + i];

    #pragma unroll
    for (int off = 1; off < 8; off <<= 1) {
        dotS += __shfl_xor(dotS, off);
        Zp   += __shfl_xor(Zp, off);
    }

    float loss = 0.f;
    int valid = 0;
    if (g == 0) {
        const float nr = nrm[i];
        const float C = (float)(long long)cntfix[lab] - 1.0f;
        const float lse = invt * nr + LN2 * __builtin_amdgcn_logf(Zp);
        const float P_nat = invt * (dotS - nr);
        if (C > 0.f) {
            loss = -(BASE_TEMP * invt) * (P_nat - C * lse) / (C + 1e-8f);
            valid = 1;
        }
    }
    loss += __shfl_down(loss, 8);   valid += __shfl_down(valid, 8);
    loss += __shfl_down(loss, 16);  valid += __shfl_down(valid, 16);
    loss += __shfl_down(loss, 32);  valid += __shfl_down(valid, 32);

    __shared__ float rl[4];
    __shared__ int rv[4];
    if ((tid & 63) == 0) { rl[tid >> 6] = loss; rv[tid >> 6] = valid; }
    __syncthreads();
    if (tid == 0) {
        float bt = (rl[0] + rl[1]) + (rl[2] + rl[3]);
        int bv = (rv[0] + rv[1]) + (rv[2] + rv[3]);
        atomicAdd(lossfix, fix64(bt));
        atomicAdd(validfix, (u64)bv);
        __threadfence();
        unsigned int t = atomicAdd(done, 1u);
        if (t == gridDim.x - 1) {     // last block finalizes (deterministic)
            u64 L = atomicAdd(lossfix, 0ull);
            u64 V = atomicAdd(validfix, 0ull);
            double T = (double)(long long)L * (1.0 / (double)FIX_SCALE);
            double N = (double)(long long)V;
            out[0] = (N > 0.0) ? (float)(T / fmax(N, 1.0)) : 0.f;
        }
    }
}

extern "C" void kernel_launch(void* const* d_in, const int* in_sizes, int n_in,
                              void* d_out, int out_size, void* d_ws, size_t ws_size,
                              hipStream_t stream) {
    const float* E = (const float*)d_in[0];
    const int* labels = (const int*)d_in[1];
    float* out = (float*)d_out;
    char* ws = (char*)d_ws;

    // workspace layout (~4.6 MB)
    const size_t OFF_EBF  = 0;                        // 2 MB tiled bf16
    const size_t OFF_EBS  = (size_t)2 << 20;          // 2 MB tiled bf16 (scaled)
    const size_t OFF_ATOM = (size_t)4 << 20;          // 4 KB accumulators
    const size_t OFF_NRM  = OFF_ATOM + 4096;          // 32 KB row norms
    const size_t OFF_PART = OFF_NRM + (size_t)B_ROWS * 4;  // 512 KB part

    __bf16* Ebf = (__bf16*)(ws + OFF_EBF);
    __bf16* Ebs = (__bf16*)(ws + OFF_EBS);
    u64* Sfix = (u64*)(ws + OFF_ATOM);                // [0..383]
    u64* cntfix = Sfix + 384;                         // [384..386]
    u64* lossfix = Sfix + 388;
    u64* validfix = Sfix + 389;
    unsigned int* done = (unsigned int*)(Sfix + 390);
    float* nrm = (float*)(ws + OFF_NRM);
    float* part = (float*)(ws + OFF_PART);

    kz_zero<<<1, 256, 0, stream>>>(Sfix);
    k0_prep<<<256, 256, 0, stream>>>(E, labels, Ebf, Ebs, nrm, Sfix, cntfix);
    k2_stats<<<dim3(64, NSPLIT), 256, 0, stream>>>(Ebf, Ebs, labels, nrm, part);
    k3_rowloss<<<256, 256, 0, stream>>>(E, labels, Sfix, cntfix, nrm, part,
                                        lossfix, validfix, done, out);
}

// Round 11
// 48.457 us; speedup vs baseline: 1.3808x; 1.3808x over previous
//
#include <hip/hip_runtime.h>
#include <hip/hip_bf16.h>

// ClassBalancedSupConLoss, B=8192, D=128.
// loss_i = -(BASE/t_i)*[P_i - C_i*lse_i]/(C_i+eps)
//   P_i   = invt_i*(e_i.S_{c(i)} - ||e_i||^2)      (fp32 closed form)
//   C_i   = count_{c(i)} - 1
//   lse_i = invt_i*||e_i||^2 + ln(Z_i),  Z_i = sum_j exp2(v_ij - m_i),
//           m_i = invt_i*log2e*||e_i||^2 (fixed reference; exact identity)
// r11 k2: W=2 (two pre-scaled B-tiles/wave, r9-proven) + A-tile staged in
// LDS double-buffer shared by 4 waves (global A traffic 512->64 MB; manual
// prefetch r10-proven load-bearing). Dual 8-deep MFMA chains a0/a1 init to
// -m0/-m1 so exp2 args come straight off the matrix pipe.
// Ebf/Ebs in MFMA-fragment-tiled order (validated r4+):
//   (r,k) -> tile r>>5, chunk k>>4, lane (r&31)+((k>>3)&1)*32, e k&7.
// LESSON r8: launch_bounds min-waves caps VGPR -> k2 uses (256,2) = cap 256.
// 3 dispatches: k0 (plain per-block partials, no atomics), k2 (+aux blocks
// reduce S/counts and zero loss ticket), k3 (ticket finalize).

#define B_ROWS 8192
#define D_DIM 128
#define NSPLIT 16
#define JRANGE (B_ROWS / NSPLIT)     // 512
#define NSTEPS (JRANGE / 32)         // 16
#define BASE_TEMP 0.07f
#define LOG2E 1.4426950408889634f
#define LN2 0.6931471805599453f
#define FIX_SCALE 1048576.0f         // 2^20

typedef __bf16 bf16x8 __attribute__((ext_vector_type(8)));
typedef __bf16 bf16x4 __attribute__((ext_vector_type(4)));
typedef float floatx16 __attribute__((ext_vector_type(16)));
typedef unsigned long long u64;

__device__ __forceinline__ float class_invtemp(int lbl) {
    return (lbl == 0) ? 12.5f : ((lbl == 1) ? 20.0f : 10.0f);
}

__device__ __forceinline__ u64 fix64(float v) {
    return (u64)(long long)llrintf(v * FIX_SCALE);
}

// ---- K0: cast->tiled Ebf + pre-scaled Ebs + row norms; per-block partials ----
__global__ __launch_bounds__(256) void k0_prep(
        const float* __restrict__ E, const int* __restrict__ labels,
        __bf16* __restrict__ Ebf, __bf16* __restrict__ Ebs,
        float* __restrict__ nrm,
        float* __restrict__ Spart /*[256][3][128]*/,
        int* __restrict__ cntpart /*[256][4]*/) {
    const int blk = blockIdx.x;          // 256 blocks x 32 rows
    const int tid = threadIdx.x;
    const int row0 = blk * 32;

    __shared__ float sh[3][128];
    __shared__ int scnt[3];
    if (tid < 3) scnt[tid] = 0;

    // pass 1: cast to tiled fragment layout (+scaled copy) + row norms
    const float4* src = reinterpret_cast<const float4*>(E + (size_t)row0 * D_DIM);
    #pragma unroll
    for (int p = 0; p < 4; ++p) {
        int idx = p * 256 + tid;         // 1024 float4 = 32 rows x 32 k4
        float4 v = src[idx];
        int r = idx >> 5, k4 = idx & 31;
        int R = row0 + r;
        float sc = class_invtemp(labels[R]) * LOG2E;
        int T = R >> 5;
        int l = (R & 31) + ((k4 >> 1) & 1) * 32;
        int c = k4 >> 2;
        size_t dst = (size_t)T * 4096 + c * 512 + l * 8 + (k4 & 1) * 4;
        bf16x4 o  = { (__bf16)v.x, (__bf16)v.y, (__bf16)v.z, (__bf16)v.w };
        bf16x4 os = { (__bf16)(v.x * sc), (__bf16)(v.y * sc),
                      (__bf16)(v.z * sc), (__bf16)(v.w * sc) };
        *reinterpret_cast<bf16x4*>(Ebf + dst) = o;
        *reinterpret_cast<bf16x4*>(Ebs + dst) = os;
        float s = v.x * v.x + v.y * v.y + v.z * v.z + v.w * v.w;
        s += __shfl_xor(s, 1);  s += __shfl_xor(s, 2);  s += __shfl_xor(s, 4);
        s += __shfl_xor(s, 8);  s += __shfl_xor(s, 16);
        if ((tid & 31) == 0) nrm[R] = s;   // 32 consecutive lanes = one row
    }

    // pass 2: per-block class sums (L1/L2-hot), plain stores
    const int d = tid & 127, half = tid >> 7;
    float s0 = 0.f, s1 = 0.f, s2 = 0.f;
    #pragma unroll 4
    for (int r2 = 0; r2 < 16; ++r2) {
        int r = row0 + half * 16 + r2;
        float v = E[(size_t)r * D_DIM + d];
        int l = labels[r];
        s0 += (l == 0) ? v : 0.f;
        s1 += (l == 1) ? v : 0.f;
        s2 += (l == 2) ? v : 0.f;
    }
    if (half == 1) { sh[0][d] = s0; sh[1][d] = s1; sh[2][d] = s2; }
    if (tid < 32) atomicAdd(&scnt[labels[row0 + tid]], 1);   // LDS int: exact
    __syncthreads();
    if (half == 0) {
        Spart[((size_t)blk * 3 + 0) * 128 + d] = s0 + sh[0][d];
        Spart[((size_t)blk * 3 + 1) * 128 + d] = s1 + sh[1][d];
        Spart[((size_t)blk * 3 + 2) * 128 + d] = s2 + sh[2][d];
    }
    if (tid < 3) cntpart[blk * 4 + tid] = scnt[tid];
}

// ---- K2: LDS-staged A, W=2 dual-chain MFMA + aux reductions ----
// grid (32 itiles, NSPLIT); block 256 = 4 waves; wave owns 64 i-cols.
__global__ __launch_bounds__(256, 2) void k2_stats(
        const __bf16* __restrict__ Ebf, const __bf16* __restrict__ Ebs,
        const int* __restrict__ labels, const float* __restrict__ nrm,
        float* __restrict__ part /*[NSPLIT][B]*/,
        const float* __restrict__ Spart, const int* __restrict__ cntpart,
        float* __restrict__ S /*[3*128]*/, float* __restrict__ counts /*[4]*/,
        u64* __restrict__ lossfix, u64* __restrict__ validfix,
        unsigned int* __restrict__ done) {
    __shared__ __bf16 Ab[2][4096];       // 16 KB A-tile double buffer

    const int tid = threadIdx.x;
    const int lane = tid & 63;
    const int wave = tid >> 6;
    const int itile = blockIdx.x;        // 0..31 (256 i-cols per block)
    const int split = blockIdx.y;        // 0..NSPLIT-1
    const int col = lane & 31;
    const int icol0 = itile * 256 + wave * 64 + col;
    const int icol1 = icol0 + 32;

    const float negm0 = -class_invtemp(labels[icol0]) * LOG2E * nrm[icol0];
    const float negm1 = -class_invtemp(labels[icol1]) * LOG2E * nrm[icol1];

    // two B frags (i side), pre-scaled (Ebs), register-resident
    const int iT0 = itile * 8 + wave * 2;
    const __bf16* b0 = Ebs + (size_t)iT0 * 4096 + lane * 8;
    bf16x8 Bf0[8], Bf1[8];
    #pragma unroll
    for (int c = 0; c < 8; ++c) {
        Bf0[c] = *reinterpret_cast<const bf16x8*>(b0 + c * 512);
        Bf1[c] = *reinterpret_cast<const bf16x8*>(b0 + 4096 + c * 512);
    }

    // A tiles (j side): Ebf tiles [split*NSTEPS, +NSTEPS), 8 KB contiguous
    const __bf16* abase = Ebf + (size_t)split * NSTEPS * 4096;

    // prologue: stage tile 0 (256 thr x 2 float4 = 8 KB)
    {
        const float4* s0 = reinterpret_cast<const float4*>(abase);
        float4* d0 = reinterpret_cast<float4*>(&Ab[0][0]);
        d0[tid] = s0[tid];
        d0[tid + 256] = s0[tid + 256];
    }
    __syncthreads();

    float Zacc0[4], Zacc1[4];
    #pragma unroll
    for (int q = 0; q < 4; ++q) { Zacc0[q] = 0.f; Zacc1[q] = 0.f; }

    for (int s = 0; s < NSTEPS; ++s) {
        // issue next-tile global loads FIRST (in flight across whole step)
        float4 nxt0, nxt1;
        if (s + 1 < NSTEPS) {
            const float4* sp = reinterpret_cast<const float4*>(
                abase + (size_t)(s + 1) * 4096);
            nxt0 = sp[tid];
            nxt1 = sp[tid + 256];
        }

        // ds_read current A fragments
        const __bf16* abuf = &Ab[s & 1][0];
        bf16x8 A[8];
        #pragma unroll
        for (int c = 0; c < 8; ++c)
            A[c] = *reinterpret_cast<const bf16x8*>(abuf + c * 512 + lane * 8);

        // dual 8-deep chains: a0 = full dot vs B0 (init -m0), a1 vs B1
        floatx16 a0, a1;
        #pragma unroll
        for (int r = 0; r < 16; ++r) { a0[r] = negm0; a1[r] = negm1; }
        #pragma unroll
        for (int c = 0; c < 8; ++c) {
            a0 = __builtin_amdgcn_mfma_f32_32x32x16_bf16(A[c], Bf0[c], a0, 0, 0, 0);
            a1 = __builtin_amdgcn_mfma_f32_32x32x16_bf16(A[c], Bf1[c], a1, 0, 0, 0);
        }

        #pragma unroll
        for (int q = 0; q < 4; ++q) {
            Zacc0[q] += (__builtin_amdgcn_exp2f(a0[4 * q])
                       + __builtin_amdgcn_exp2f(a0[4 * q + 1]))
                      + (__builtin_amdgcn_exp2f(a0[4 * q + 2])
                       + __builtin_amdgcn_exp2f(a0[4 * q + 3]));
            Zacc1[q] += (__builtin_amdgcn_exp2f(a1[4 * q])
                       + __builtin_amdgcn_exp2f(a1[4 * q + 1]))
                      + (__builtin_amdgcn_exp2f(a1[4 * q + 2])
                       + __builtin_amdgcn_exp2f(a1[4 * q + 3]));
        }

        // write next tile into the other buffer; one barrier per step
        if (s + 1 < NSTEPS) {
            float4* dn = reinterpret_cast<float4*>(&Ab[(s + 1) & 1][0]);
            dn[tid] = nxt0;
            dn[tid + 256] = nxt1;
        }
        __syncthreads();
    }

    float Zt0 = (Zacc0[0] + Zacc0[1]) + (Zacc0[2] + Zacc0[3]);
    float Zt1 = (Zacc1[0] + Zacc1[1]) + (Zacc1[2] + Zacc1[3]);
    Zt0 += __shfl_xor(Zt0, 32);          // lanes l, l+32 hold same i-col
    Zt1 += __shfl_xor(Zt1, 32);
    if (lane < 32) {
        part[(size_t)split * B_ROWS + icol0] = Zt0;
        part[(size_t)split * B_ROWS + icol1] = Zt1;
    }

    // ---- aux (runs before k3 via stream order): S, counts, ticket zero ----
    if (split == 0) {
        if (itile < 3 && tid < 128) {
            float a = 0.f;
            #pragma unroll 8
            for (int g = 0; g < 256; ++g)
                a += Spart[((size_t)g * 3 + itile) * 128 + tid];
            S[itile * 128 + tid] = a;
        } else if (itile == 3 && tid < 3) {
            int a = 0;
            #pragma unroll 8
            for (int g = 0; g < 256; ++g) a += cntpart[g * 4 + tid];
            counts[tid] = (float)a;
        } else if (itile == 4 && tid == 0) {
            *lossfix = 0ull;
            *validfix = 0ull;
            *done = 0u;
        }
    }
}

// ---- K3: per-row loss (8 thr/row), fixed-point accumulate + ticket ----
__global__ __launch_bounds__(256) void k3_rowloss(
        const float* __restrict__ E, const int* __restrict__ labels,
        const float* __restrict__ S, const float* __restrict__ counts,
        const float* __restrict__ nrm, const float* __restrict__ part,
        u64* __restrict__ lossfix, u64* __restrict__ validfix,
        unsigned int* __restrict__ done, float* __restrict__ out) {
    __shared__ float sS[384];
    const int tid = threadIdx.x;
    if (tid < 128) {
        sS[tid]       = S[tid];
        sS[128 + tid] = S[128 + tid];
        sS[256 + tid] = S[256 + tid];
    }
    __syncthreads();

    const int r = tid >> 3, g = tid & 7;       // 32 rows/block, 8 thr/row
    const int i = blockIdx.x * 32 + r;
    const int lab = labels[i];
    const float invt = class_invtemp(lab);

    const float4* er = reinterpret_cast<const float4*>(E + (size_t)i * D_DIM);
    const float4* sr = reinterpret_cast<const float4*>(&sS[lab * 128]);
    float dotS = 0.f;
    #pragma unroll
    for (int q = 0; q < 4; ++q) {
        float4 v = er[g * 4 + q];
        float4 s = sr[g * 4 + q];
        dotS += v.x * s.x + v.y * s.y + v.z * s.z + v.w * s.w;
    }
    float Zp = 0.f;
    #pragma unroll
    for (int p = 0; p < NSPLIT / 8; ++p)
        Zp += part[(size_t)(g + p * 8) * B_ROWS + i];

    #pragma unroll
    for (int off = 1; off < 8; off <<= 1) {
        dotS += __shfl_xor(dotS, off);
        Zp   += __shfl_xor(Zp, off);
    }

    float loss = 0.f;
    int valid = 0;
    if (g == 0) {
        const float nr = nrm[i];
        const float C = counts[lab] - 1.0f;
        const float lse = invt * nr + LN2 * __builtin_amdgcn_logf(Zp);
        const float P_nat = invt * (dotS - nr);
        if (C > 0.f) {
            loss = -(BASE_TEMP * invt) * (P_nat - C * lse) / (C + 1e-8f);
            valid = 1;
        }
    }
    loss += __shfl_down(loss, 8);   valid += __shfl_down(valid, 8);
    loss += __shfl_down(loss, 16);  valid += __shfl_down(valid, 16);
    loss += __shfl_down(loss, 32);  valid += __shfl_down(valid, 32);

    __shared__ float rl[4];
    __shared__ int rv[4];
    if ((tid & 63) == 0) { rl[tid >> 6] = loss; rv[tid >> 6] = valid; }
    __syncthreads();
    if (tid == 0) {
        float bt = (rl[0] + rl[1]) + (rl[2] + rl[3]);
        int bv = (rv[0] + rv[1]) + (rv[2] + rv[3]);
        atomicAdd(lossfix, fix64(bt));
        atomicAdd(validfix, (u64)bv);
        __threadfence();
        unsigned int t = atomicAdd(done, 1u);
        if (t == gridDim.x - 1) {     // last block finalizes (deterministic)
            u64 L = atomicAdd(lossfix, 0ull);
            u64 V = atomicAdd(validfix, 0ull);
            double T = (double)(long long)L * (1.0 / (double)FIX_SCALE);
            double N = (double)(long long)V;
            out[0] = (N > 0.0) ? (float)(T / fmax(N, 1.0)) : 0.f;
        }
    }
}

extern "C" void kernel_launch(void* const* d_in, const int* in_sizes, int n_in,
                              void* d_out, int out_size, void* d_ws, size_t ws_size,
                              hipStream_t stream) {
    const float* E = (const float*)d_in[0];
    const int* labels = (const int*)d_in[1];
    float* out = (float*)d_out;
    char* ws = (char*)d_ws;

    // workspace layout (~5.1 MB)
    const size_t OFF_EBF   = 0;                        // 2 MB tiled bf16
    const size_t OFF_EBS   = (size_t)2 << 20;          // 2 MB tiled bf16 (scaled)
    const size_t OFF_NRM   = (size_t)4 << 20;          // 32 KB row norms
    const size_t OFF_SPART = OFF_NRM + 32768;          // 384 KB
    const size_t OFF_CNTP  = OFF_SPART + 393216;       // 4 KB
    const size_t OFF_S     = OFF_CNTP + 4096;          // 1.5 KB
    const size_t OFF_MISC  = OFF_S + 2048;             // counts + ticket
    const size_t OFF_PART  = OFF_MISC + 256;           // 512 KB part

    __bf16* Ebf = (__bf16*)(ws + OFF_EBF);
    __bf16* Ebs = (__bf16*)(ws + OFF_EBS);
    float* nrm = (float*)(ws + OFF_NRM);
    float* Spart = (float*)(ws + OFF_SPART);
    int* cntpart = (int*)(ws + OFF_CNTP);
    float* S = (float*)(ws + OFF_S);
    float* counts = (float*)(ws + OFF_MISC);           // 4 f32
    u64* lossfix = (u64*)(ws + OFF_MISC + 16);
    u64* validfix = (u64*)(ws + OFF_MISC + 24);
    unsigned int* done = (unsigned int*)(ws + OFF_MISC + 32);
    float* part = (float*)(ws + OFF_PART);

    k0_prep<<<256, 256, 0, stream>>>(E, labels, Ebf, Ebs, nrm, Spart, cntpart);
    k2_stats<<<dim3(32, NSPLIT), 256, 0, stream>>>(
        Ebf, Ebs, labels, nrm, part, Spart, cntpart, S, counts,
        lossfix, validfix, done);
    k3_rowloss<<<256, 256, 0, stream>>>(E, labels, S, counts, nrm, part,
                                        lossfix, validfix, done, out);
}